// Round 12
// baseline (505.135 us; speedup 1.0000x reference)
//
#include <hip/hip_runtime.h>
#include <hip/hip_fp16.h>
#include <stdint.h>
#include <math.h>

#define HID 64
#define DIN 128
#define DOUT 40
#define N_LAYERS 8
#define CSR_CAP 768   // 32-node tile: mean 512 edges, std ~23; overflow -> global fallback

typedef _Float16 half8 __attribute__((ext_vector_type(8)));
typedef float f32x4 __attribute__((ext_vector_type(4)));

static inline int cdiv(int a, int b) { return (a + b - 1) / b; }

// ---------- edge-index layout helpers ----------
__device__ __forceinline__ int edge_src(const uint32_t* ei, int is64, int E, int e) {
    return is64 ? (int)ei[2 * e] : (int)ei[e];
}
__device__ __forceinline__ int edge_dst(const uint32_t* ei, int is64, int E, int e) {
    return is64 ? (int)ei[2 * (size_t)E + 2 * e] : (int)ei[(size_t)E + e];
}

// ---------- merged setup: zero cnt+cnt_part | Bp | W1h | detect i64 | W2 split ----
// blocks [0,nb0): zero 9N ints; [nb0,nb0+8): Bp; nb0+8: W1h; nb0+9: detect;
// nb0+10: W2hi/lo.  grid MUST be nb0 + N_LAYERS + 3.
__global__ void setup(const uint32_t* __restrict__ ei, int* __restrict__ flag,
                      const float* __restrict__ convw, __half* __restrict__ Bp,
                      const float* __restrict__ W1, __half* __restrict__ W1h,
                      const float* __restrict__ W2, __half* __restrict__ W2h,
                      __half* __restrict__ W2l, int* __restrict__ cnt, int n, int nb0) {
    int b = blockIdx.x;
    int t = threadIdx.x;
    if (b < nb0) {
        int v = b * 256 + t;
        if (v < 9 * n) cnt[v] = 0;
        return;
    }
    int r = b - nb0;
    if (r < N_LAYERS) {
        // Bp_i = fp16(beta_i * W_i + (1-beta_i) * I), stored transposed [n][k]
        float beta = logf(0.5f / (float)(r + 1) + 1.f);
        const float* W = convw + (size_t)r * HID * HID;
        __half* out = Bp + (size_t)r * HID * HID;
        for (int idx = t; idx < HID * HID; idx += 256) {
            int k = idx >> 6, nn = idx & 63;
            float v = beta * W[k * HID + nn] + ((k == nn) ? (1.f - beta) : 0.f);
            out[nn * HID + k] = __float2half(v);
        }
    } else if (r == N_LAYERS) {
        // W1h = fp16(W1^T) : [64 n][128 k]
        for (int idx = t; idx < DIN * HID; idx += 256) {
            int nn = idx >> 7, k = idx & 127;
            W1h[nn * DIN + k] = __float2half(W1[k * HID + nn]);
        }
    } else if (r == N_LAYERS + 1) {
        // detect int64 vs int32 storage of edge_index
        if (t < 64) {
            uint32_t wv = ei[2 * t + 1];
            unsigned long long nz = __ballot(wv != 0u);
            if (t == 0) *flag = (nz == 0ull) ? 1 : 0;
        }
    } else {
        // W2 split into hi+lo fp16, transposed [48 n][64 k] (rows 40..47 zero)
        for (int idx = t; idx < 48 * 64; idx += 256) {
            int nn = idx >> 6, k = idx & 63;
            float v = (nn < DOUT) ? W2[k * DOUT + nn] : 0.f;
            __half hi = __float2half(v);
            W2h[idx] = hi;
            W2l[idx] = __float2half(v - __half2float(hi));
        }
    }
}

// ---------- CSR construction: XCD-local partial histograms, zero-overhead scatter --
// count atomics go to copy x = blockIdx&7; consecutive blocks round-robin the 8
// XCDs, so each copy's lines stay resident in one XCD's L2 (no cross-XCD
// ping-pong). scan3 folds row_start INTO the per-copy offsets, so scatter does
// exactly ONE random read (cnt_part[x*N+d]) -- same count as the R7 scatter.
__global__ void count_pos(const uint32_t* __restrict__ ei, const int* __restrict__ flag,
                          int* __restrict__ cnt_part, int* __restrict__ pw,
                          int E, int n) {
    int e = blockIdx.x * blockDim.x + threadIdx.x;
    if (e >= E) return;
    int is64 = *flag;
    int d = edge_dst(ei, is64, E, e);
    int x = blockIdx.x & 7;
    pw[e] = atomicAdd(&cnt_part[(size_t)x * n + d], 1);
}

// fold 8 partial histograms into cnt; rewrite cnt_part[x][v] as running prefix
__global__ void reduce_hist(int* __restrict__ cnt_part, int* __restrict__ cnt, int n) {
    int v = blockIdx.x * blockDim.x + threadIdx.x;
    if (v >= n) return;
    int s = 0;
#pragma unroll
    for (int x = 0; x < 8; x++) {
        int c = cnt_part[(size_t)x * n + v];
        cnt_part[(size_t)x * n + v] = s;
        s += c;
    }
    cnt[v] = s;
}

__global__ void scan1(const int* __restrict__ cnt, int* __restrict__ row_start,
                      int* __restrict__ blocksum, int n) {
    __shared__ int sh[256];
    int t = threadIdx.x;
    int v = blockIdx.x * 256 + t;
    int val = (v < n) ? cnt[v] : 0;
    sh[t] = val;
    __syncthreads();
    for (int o = 1; o < 256; o <<= 1) {
        int y = (t >= o) ? sh[t - o] : 0;
        __syncthreads();
        sh[t] += y;
        __syncthreads();
    }
    if (v < n) row_start[v] = sh[t] - val;
    if (t == 255) blocksum[blockIdx.x] = sh[255];
}

__global__ void scan2(int* __restrict__ blocksum, int nb) {
    __shared__ int sh[512];
    int t = threadIdx.x;
    int val = (t < nb) ? blocksum[t] : 0;
    sh[t] = val;
    __syncthreads();
    for (int o = 1; o < 512; o <<= 1) {
        int y = (t >= o) ? sh[t - o] : 0;
        __syncthreads();
        sh[t] += y;
        __syncthreads();
    }
    if (t < nb) blocksum[t] = sh[t] - val;
}

// scan3: finalize row_start, dinv, fold row_start into per-copy offsets
__global__ void scan3(int* __restrict__ row_start, const int* __restrict__ blocksum,
                      const int* __restrict__ cnt, float* __restrict__ dinv,
                      int* __restrict__ cnt_part, int n) {
    int v = blockIdx.x * 256 + threadIdx.x;
    if (v < n) {
        int rs = row_start[v] + blocksum[v >> 8];
        row_start[v] = rs;
        dinv[v] = rsqrtf((float)(cnt[v] + 1));
#pragma unroll
        for (int x = 0; x < 8; x++) cnt_part[(size_t)x * n + v] += rs;
    }
}

__global__ void scatter_pos(const uint32_t* __restrict__ ei, const int* __restrict__ flag,
                            const int* __restrict__ cnt_part, const int* __restrict__ pw,
                            int* __restrict__ csr_src, int E, int n) {
    int e = blockIdx.x * blockDim.x + threadIdx.x;
    if (e >= E) return;
    int is64 = *flag;
    int s = edge_src(ei, is64, E, e);
    int d = edge_dst(ei, is64, E, e);
    int x = blockIdx.x & 7;
    csr_src[cnt_part[(size_t)x * n + d] + pw[e]] = s;
}

// ---------- MFMA input layer: h0h = fp16(relu(x@W1+b1)); hp = fp16(dinv*h0) ----------
__global__ void __launch_bounds__(256) mlp_in_mfma(
        const float* __restrict__ x, const __half* __restrict__ W1h,
        const float* __restrict__ b1, const float* __restrict__ dinv,
        __half2* __restrict__ hp2, __half2* __restrict__ h0h2, int n) {
    __shared__ __align__(16) ushort Bs[64 * 136];
    __shared__ __align__(16) ushort As[128 * 136];
    int t = threadIdx.x;
    {
        const __half2* W2v = (const __half2*)W1h;
        for (int i = t; i < 64 * 64; i += 256) {
            int bn = i >> 6, kp = i & 63;
            *(__half2*)&Bs[bn * 136 + 2 * kp] = W2v[bn * 64 + kp];
        }
    }
    int node0 = blockIdx.x * 128;
    {
        const float4* x4 = (const float4*)x;
        for (int i = t; i < 128 * 32; i += 256) {
            int nd = i >> 5, q = i & 31;
            int node = node0 + nd;
            float4 xv = (node < n) ? x4[(size_t)node * 32 + q]
                                   : make_float4(0.f, 0.f, 0.f, 0.f);
            *(__half2*)&As[nd * 136 + q * 4]     = __floats2half2_rn(xv.x, xv.y);
            *(__half2*)&As[nd * 136 + q * 4 + 2] = __floats2half2_rn(xv.z, xv.w);
        }
    }
    __syncthreads();
    int lane = t & 63, wv = t >> 6;
    int nl = lane & 15, quad = lane >> 4;
    int m_base = wv * 32;
    f32x4 C[2][4];
#pragma unroll
    for (int mt = 0; mt < 2; mt++)
#pragma unroll
        for (int nt = 0; nt < 4; nt++) C[mt][nt] = (f32x4)0.f;
#pragma unroll
    for (int kc = 0; kc < 4; kc++) {
        half8 a[2], b[4];
#pragma unroll
        for (int mt = 0; mt < 2; mt++)
            a[mt] = *(const half8*)&As[(m_base + mt * 16 + nl) * 136 + kc * 32 + quad * 8];
#pragma unroll
        for (int nt = 0; nt < 4; nt++)
            b[nt] = *(const half8*)&Bs[(nt * 16 + nl) * 136 + kc * 32 + quad * 8];
#pragma unroll
        for (int mt = 0; mt < 2; mt++)
#pragma unroll
            for (int nt = 0; nt < 4; nt++)
                C[mt][nt] = __builtin_amdgcn_mfma_f32_16x16x32_f16(a[mt], b[nt],
                                                                   C[mt][nt], 0, 0, 0);
    }
    __syncthreads();
#pragma unroll
    for (int nt = 0; nt < 4; nt++) {
        float bias = b1[nt * 16 + nl];
#pragma unroll
        for (int mt = 0; mt < 2; mt++) {
#pragma unroll
            for (int reg = 0; reg < 4; reg++) {
                int nd = m_base + mt * 16 + quad * 4 + reg;
                float v = fmaxf(C[mt][nt][reg] + bias, 0.f);
                As[nd * 72 + nt * 16 + nl] = __half_as_ushort(__float2half(v));
            }
        }
    }
    __syncthreads();
    for (int i = t; i < 128 * 32; i += 256) {
        int nd = i >> 5, kp = i & 31;
        int node = node0 + nd;
        if (node < n) {
            __half2 h = *(const __half2*)&As[nd * 72 + 2 * kp];
            h0h2[(size_t)node * 32 + kp] = h;
            float dv = dinv[node];
            float2 f = __half22float2(h);
            hp2[(size_t)node * 32 + kp] = __floats2half2_rn(f.x * dv, f.y * dv);
        }
    }
}

// ---------- fused layer (exact R7 winner): register gather + Bs staging ----------
// 256 threads = 32 groups x 8 lanes; 32-node tile; group g owns node node0+g.
// Lane sub owns feature chunk [sub*8, sub*8+8): accumulates the node's edges in
// registers (no shuffles, no atomics, no per-node sync). B' staged in LDS.
// Last layer: extra double-fp16 W2 MFMA phase writes y directly.
__global__ void __launch_bounds__(256) gcnii_fused(
        const __half* __restrict__ hp, const __half* __restrict__ h0,
        const int* __restrict__ row_start, const int* __restrict__ csr_src,
        const float* __restrict__ dinv, const __half* __restrict__ Bp,
        const __half* __restrict__ W2h, const __half* __restrict__ W2l,
        const float* __restrict__ b2, int is_last,
        __half* __restrict__ hpn, float* __restrict__ y, int n, int E) {
    __shared__ __align__(16) ushort Bs[64 * 72];       // B' [n][k], pad +8    9216B
    __shared__ __align__(16) ushort As[32 * 72];       // rows / result        4608B
    __shared__ int csr_lds[CSR_CAP];                   //                      3072B
    __shared__ int rs_lds[33];                         // row offsets rel. to ts
    int t = threadIdx.x;
    int node0 = blockIdx.x * 32;
    int grp = t >> 3, sub = t & 7;                     // 32 groups x 8 lanes

    // ---- stage B', CSR slice, row offsets (all independent loads) ----
    for (int i = t; i < 512; i += 256) {
        int bn = i >> 3, s8 = i & 7;
        *(half8*)&Bs[bn * 72 + s8 * 8] = *(const half8*)(Bp + bn * 64 + s8 * 8);
    }
    int ts = row_start[node0];                         // broadcast load
    int te = (node0 + 32 < n) ? row_start[node0 + 32] : E;
    int ne = te - ts;
    int staged = ne < CSR_CAP ? ne : CSR_CAP;
    for (int i = t; i < staged; i += 256) csr_lds[i] = csr_src[ts + i];
    if (t < 33) {
        int v = node0 + t;
        rs_lds[t] = ((v < n) ? row_start[v] : E) - ts;
    }
    __syncthreads();

    // ---- gather: group g accumulates node node0+g's neighbor rows in registers ----
    int v = node0 + grp;
    int j = rs_lds[grp];
    int end = rs_lds[grp + 1];
    float acc[8];
#pragma unroll
    for (int q = 0; q < 8; q++) acc[q] = 0.f;
    if (ne <= CSR_CAP) {
        int e = j;
        for (; e + 4 <= end; e += 4) {
            int s0 = csr_lds[e],     s1 = csr_lds[e + 1];
            int s2 = csr_lds[e + 2], s3 = csr_lds[e + 3];
            if ((unsigned)s0 >= (unsigned)n) s0 = 0;   // fault insurance
            if ((unsigned)s1 >= (unsigned)n) s1 = 0;
            if ((unsigned)s2 >= (unsigned)n) s2 = 0;
            if ((unsigned)s3 >= (unsigned)n) s3 = 0;
            half8 h0v = *(const half8*)(hp + (size_t)s0 * 64 + sub * 8);
            half8 h1v = *(const half8*)(hp + (size_t)s1 * 64 + sub * 8);
            half8 h2v = *(const half8*)(hp + (size_t)s2 * 64 + sub * 8);
            half8 h3v = *(const half8*)(hp + (size_t)s3 * 64 + sub * 8);
#pragma unroll
            for (int q = 0; q < 8; q++)
                acc[q] += ((float)h0v[q] + (float)h1v[q]) + ((float)h2v[q] + (float)h3v[q]);
        }
        for (; e < end; ++e) {
            int s = csr_lds[e];
            if ((unsigned)s >= (unsigned)n) s = 0;
            half8 hv = *(const half8*)(hp + (size_t)s * 64 + sub * 8);
#pragma unroll
            for (int q = 0; q < 8; q++) acc[q] += (float)hv[q];
        }
    } else {    // overflow tile (essentially never at this distribution)
        for (int e = j; e < end; ++e) {
            int s = csr_src[ts + e];
            if ((unsigned)s >= (unsigned)n) s = 0;
            half8 hv = *(const half8*)(hp + (size_t)s * 64 + sub * 8);
#pragma unroll
            for (int q = 0; q < 8; q++) acc[q] += (float)hv[q];
        }
    }
    // ---- blend + fp16 pack (self term + residual) ----
    {
        half8 o;
        if (v < n) {
            float sc = 0.9f * dinv[v];
            half8 hsv = *(const half8*)(hp + (size_t)v * 64 + sub * 8);
            half8 h0v = *(const half8*)(h0 + (size_t)v * 64 + sub * 8);
#pragma unroll
            for (int q = 0; q < 8; q++)
                o[q] = (_Float16)(sc * (acc[q] + (float)hsv[q]) + 0.1f * (float)h0v[q]);
        } else {
#pragma unroll
            for (int q = 0; q < 8; q++) o[q] = (_Float16)0.f;
        }
        *(half8*)&As[grp * 72 + sub * 8] = o;
    }
    __syncthreads();
    // ---- MFMA 32x64 = 2 strips x 4 col-tiles over 4 waves ----
    int lane = t & 63, w = t >> 6;
    int nl = lane & 15, quad = lane >> 4;
    int strip = w & 1, nth = w >> 1;
    f32x4 C[2];
    C[0] = (f32x4)0.f; C[1] = (f32x4)0.f;
#pragma unroll
    for (int kc = 0; kc < 2; kc++) {
        half8 a = *(const half8*)&As[(strip * 16 + nl) * 72 + kc * 32 + quad * 8];
#pragma unroll
        for (int t2 = 0; t2 < 2; t2++) {
            int nt = nth * 2 + t2;
            half8 b = *(const half8*)&Bs[(nt * 16 + nl) * 72 + kc * 32 + quad * 8];
            C[t2] = __builtin_amdgcn_mfma_f32_16x16x32_f16(a, b, C[t2], 0, 0, 0);
        }
    }
    __syncthreads();   // strips shared by 2 waves: finish all As reads before writes
#pragma unroll
    for (int reg = 0; reg < 4; reg++) {
        int nd = strip * 16 + quad * 4 + reg;
        int node = node0 + nd;
        float dv = (!is_last && node < n) ? dinv[node] : 1.f;
#pragma unroll
        for (int t2 = 0; t2 < 2; t2++) {
            int nt = nth * 2 + t2;
            float vv = fmaxf(C[t2][reg], 0.f) * dv;
            As[nd * 72 + nt * 16 + nl] = __half_as_ushort(__float2half(vv));
        }
    }
    __syncthreads();
    if (!is_last) {
        // ---- coalesced 16B store (32 rows x 8 chunks = 256 = one round) ----
        int nd = t >> 3, s8 = t & 7;
        int node = node0 + nd;
        if (node < n)
            *(half8*)(hpn + (size_t)node * 64 + s8 * 8) = *(const half8*)&As[nd * 72 + s8 * 8];
    } else {
        // ---- fused output: y = h @ W2 + b2 (double-fp16 W2, f32 accum) ----
        for (int ct = nth; ct < 3; ct += 2) {
            f32x4 C2 = (f32x4)0.f;
#pragma unroll
            for (int kc = 0; kc < 2; kc++) {
                half8 a  = *(const half8*)&As[(strip * 16 + nl) * 72 + kc * 32 + quad * 8];
                half8 bh = *(const half8*)(W2h + (ct * 16 + nl) * 64 + kc * 32 + quad * 8);
                half8 bl = *(const half8*)(W2l + (ct * 16 + nl) * 64 + kc * 32 + quad * 8);
                C2 = __builtin_amdgcn_mfma_f32_16x16x32_f16(a, bh, C2, 0, 0, 0);
                C2 = __builtin_amdgcn_mfma_f32_16x16x32_f16(a, bl, C2, 0, 0, 0);
            }
            int col = ct * 16 + nl;
            float bias = (col < DOUT) ? b2[col] : 0.f;
#pragma unroll
            for (int reg = 0; reg < 4; reg++) {
                int nd = strip * 16 + quad * 4 + reg;
                int node = node0 + nd;
                if (node < n && col < DOUT)
                    y[(size_t)node * DOUT + col] = C2[reg] + bias;
            }
        }
    }
}

extern "C" void kernel_launch(void* const* d_in, const int* in_sizes, int n_in,
                              void* d_out, int out_size, void* d_ws, size_t ws_size,
                              hipStream_t stream) {
    const float*    x     = (const float*)d_in[0];
    const uint32_t* ei    = (const uint32_t*)d_in[1];
    const float*    W1    = (const float*)d_in[2];
    const float*    b1    = (const float*)d_in[3];
    const float*    convw = (const float*)d_in[4];
    const float*    W2    = (const float*)d_in[5];
    const float*    b2    = (const float*)d_in[6];
    float*          y     = (float*)d_out;

    int N = in_sizes[0] / DIN;
    int E = in_sizes[1] / 2;

    char* ws = (char*)d_ws;
    size_t off = 0;
    auto alloc = [&](size_t bytes) -> char* {
        char* p = ws + off;
        off = (off + bytes + 255) & ~(size_t)255;
        return p;
    };
    int*     flag      = (int*)alloc(4);
    int*     cnt       = (int*)alloc((size_t)N * 9 * 4);   // cnt + 8 partial copies
    int*     cnt_part  = cnt + N;
    int*     row_start = (int*)alloc((size_t)N * 4);
    float*   dinv      = (float*)alloc((size_t)N * 4);
    int*     blocksum  = (int*)alloc(512 * 4);
    int*     pw        = (int*)alloc((size_t)E * 4);
    int*     csr_src   = (int*)alloc((size_t)E * 4);
    __half*  Bp        = (__half*)alloc((size_t)N_LAYERS * HID * HID * 2);
    __half*  W1h       = (__half*)alloc((size_t)DIN * HID * 2);
    __half*  W2h       = (__half*)alloc((size_t)48 * HID * 2);
    __half*  W2l       = (__half*)alloc((size_t)48 * HID * 2);
    __half*  h0h       = (__half*)alloc((size_t)N * HID * 2);
    __half*  hpA       = (__half*)alloc((size_t)N * HID * 2);
    __half*  hpB       = (__half*)alloc((size_t)N * HID * 2);

    int nb0 = cdiv(9 * N, 256);
    int nb  = cdiv(N, 256);
    setup<<<nb0 + N_LAYERS + 3, 256, 0, stream>>>(ei, flag, convw, Bp, W1, W1h,
                                                  W2, W2h, W2l, cnt, N, nb0);
    count_pos<<<cdiv(E, 256), 256, 0, stream>>>(ei, flag, cnt_part, pw, E, N);
    reduce_hist<<<cdiv(N, 256), 256, 0, stream>>>(cnt_part, cnt, N);
    scan1<<<nb, 256, 0, stream>>>(cnt, row_start, blocksum, N);
    scan2<<<1, 512, 0, stream>>>(blocksum, nb);
    scan3<<<cdiv(N, 256), 256, 0, stream>>>(row_start, blocksum, cnt, dinv, cnt_part, N);
    mlp_in_mfma<<<cdiv(N, 128), 256, 0, stream>>>(x, W1h, b1, dinv,
                                                  (__half2*)hpA, (__half2*)h0h, N);
    scatter_pos<<<cdiv(E, 256), 256, 0, stream>>>(ei, flag, cnt_part, pw, csr_src, E, N);

    __half* cur = hpA;
    __half* nxt = hpB;
    for (int i = 0; i < N_LAYERS; i++) {
        int is_last = (i == N_LAYERS - 1) ? 1 : 0;
        gcnii_fused<<<cdiv(N, 32), 256, 0, stream>>>(
            cur, h0h, row_start, csr_src, dinv,
            Bp + (size_t)i * HID * HID, W2h, W2l, b2, is_last, nxt, y, N, E);
        __half* tmp = cur; cur = nxt; nxt = tmp;
    }
}

// Round 17
// 474.069 us; speedup vs baseline: 1.0655x; 1.0655x over previous
//
#include <hip/hip_runtime.h>
#include <hip/hip_fp16.h>
#include <stdint.h>
#include <math.h>

#define HID 64
#define DIN 128
#define DOUT 40
#define N_LAYERS 8
#define CSR_CAP 768   // 32-node tile: mean 512 edges, std ~23; overflow -> global fallback

typedef _Float16 half8 __attribute__((ext_vector_type(8)));
typedef float f32x4 __attribute__((ext_vector_type(4)));
typedef float f32x2 __attribute__((ext_vector_type(2)));

static inline int cdiv(int a, int b) { return (a + b - 1) / b; }

// ---------- edge-index layout helpers ----------
__device__ __forceinline__ int edge_src(const uint32_t* ei, int is64, int E, int e) {
    return is64 ? (int)ei[2 * e] : (int)ei[e];
}
__device__ __forceinline__ int edge_dst(const uint32_t* ei, int is64, int E, int e) {
    return is64 ? (int)ei[2 * (size_t)E + 2 * e] : (int)ei[(size_t)E + e];
}

// pack 8 floats -> 8 fp8 e4m3 bytes (2 dwords); word-sel args are literals
__device__ __forceinline__ uint2 pack_fp8x8(const float* f) {
    int lo = __builtin_amdgcn_cvt_pk_fp8_f32(f[0], f[1], 0, false);
    lo = __builtin_amdgcn_cvt_pk_fp8_f32(f[2], f[3], lo, true);
    int hi = __builtin_amdgcn_cvt_pk_fp8_f32(f[4], f[5], 0, false);
    hi = __builtin_amdgcn_cvt_pk_fp8_f32(f[6], f[7], hi, true);
    return make_uint2((unsigned)lo, (unsigned)hi);
}

// unpack 8 fp8 e4m3 bytes (uint2) -> 8 floats; word-sel args are LITERALS
__device__ __forceinline__ void cvt8(uint2 c, float* out) {
    f32x2 a = __builtin_amdgcn_cvt_pk_f32_fp8((int)c.x, false);  // bytes 0,1
    f32x2 b = __builtin_amdgcn_cvt_pk_f32_fp8((int)c.x, true);   // bytes 2,3
    f32x2 d = __builtin_amdgcn_cvt_pk_f32_fp8((int)c.y, false);
    f32x2 e = __builtin_amdgcn_cvt_pk_f32_fp8((int)c.y, true);
    out[0] = a.x; out[1] = a.y; out[2] = b.x; out[3] = b.y;
    out[4] = d.x; out[5] = d.y; out[6] = e.x; out[7] = e.y;
}

// ---------- merged setup: zero cnt | Bp | W1h | detect i64 | W2 split ----------
// blocks [0,nb): zero cnt; [nb,nb+8): Bp; nb+8: W1h; nb+9: detect; nb+10: W2hi/lo
// grid MUST be nb + N_LAYERS + 3.
__global__ void setup(const uint32_t* __restrict__ ei, int* __restrict__ flag,
                      const float* __restrict__ convw, __half* __restrict__ Bp,
                      const float* __restrict__ W1, __half* __restrict__ W1h,
                      const float* __restrict__ W2, __half* __restrict__ W2h,
                      __half* __restrict__ W2l, int* __restrict__ cnt, int n, int nb) {
    int b = blockIdx.x;
    int t = threadIdx.x;
    if (b < nb) {
        int v = b * 256 + t;
        if (v < n) cnt[v] = 0;
        return;
    }
    int r = b - nb;
    if (r < N_LAYERS) {
        // Bp_i = fp16(beta_i * W_i + (1-beta_i) * I), stored transposed [n][k]
        float beta = logf(0.5f / (float)(r + 1) + 1.f);
        const float* W = convw + (size_t)r * HID * HID;
        __half* out = Bp + (size_t)r * HID * HID;
        for (int idx = t; idx < HID * HID; idx += 256) {
            int k = idx >> 6, nn = idx & 63;
            float v = beta * W[k * HID + nn] + ((k == nn) ? (1.f - beta) : 0.f);
            out[nn * HID + k] = __float2half(v);
        }
    } else if (r == N_LAYERS) {
        // W1h = fp16(W1^T) : [64 n][128 k]
        for (int idx = t; idx < DIN * HID; idx += 256) {
            int nn = idx >> 7, k = idx & 127;
            W1h[nn * DIN + k] = __float2half(W1[k * HID + nn]);
        }
    } else if (r == N_LAYERS + 1) {
        // detect int64 vs int32 storage of edge_index
        if (t < 64) {
            uint32_t wv = ei[2 * t + 1];
            unsigned long long nz = __ballot(wv != 0u);
            if (t == 0) *flag = (nz == 0ull) ? 1 : 0;
        }
    } else {
        // W2 split into hi+lo fp16, transposed [48 n][64 k] (rows 40..47 zero)
        for (int idx = t; idx < 48 * 64; idx += 256) {
            int nn = idx >> 6, k = idx & 63;
            float v = (nn < DOUT) ? W2[k * DOUT + nn] : 0.f;
            __half hi = __float2half(v);
            W2h[idx] = hi;
            W2l[idx] = __float2half(v - __half2float(hi));
        }
    }
}

// ---------- merged: count_pos (atomic ticket) + input-MLP h0h ----------
// blocks [0,GC): per-edge degree count + ticket (memory-side-atomic-bound)
// blocks [GC,GC+GM): h0h = fp16(relu(x@W1+b1)), 64-node tiles, W1 frags from global.
__global__ void __launch_bounds__(256) count_mlp(
        const uint32_t* __restrict__ ei, const int* __restrict__ flag,
        int* __restrict__ cnt, int* __restrict__ pw, int E,
        const float* __restrict__ x, const __half* __restrict__ W1h,
        const float* __restrict__ b1, __half2* __restrict__ h0h2, int n, int GC) {
    __shared__ __align__(16) ushort As[64 * 136];      // 17408B (x tile / result)
    int b = blockIdx.x;
    int t = threadIdx.x;
    if (b < GC) {
        int e = b * 256 + t;
        if (e < E) {
            int is64 = *flag;
            int d = edge_dst(ei, is64, E, e);
            pw[e] = atomicAdd(&cnt[d], 1);
        }
        return;
    }
    int node0 = (b - GC) * 64;
    {
        const float4* x4 = (const float4*)x;
        for (int i = t; i < 64 * 32; i += 256) {
            int nd = i >> 5, q = i & 31;
            int node = node0 + nd;
            float4 xv = (node < n) ? x4[(size_t)node * 32 + q]
                                   : make_float4(0.f, 0.f, 0.f, 0.f);
            *(__half2*)&As[nd * 136 + q * 4]     = __floats2half2_rn(xv.x, xv.y);
            *(__half2*)&As[nd * 136 + q * 4 + 2] = __floats2half2_rn(xv.z, xv.w);
        }
    }
    __syncthreads();
    int lane = t & 63, wv = t >> 6;
    int nl = lane & 15, quad = lane >> 4;
    int m_base = wv * 16;                              // 4 waves x 16 rows
    f32x4 C[4];
#pragma unroll
    for (int nt = 0; nt < 4; nt++) C[nt] = (f32x4)0.f;
#pragma unroll
    for (int kc = 0; kc < 4; kc++) {
        half8 a = *(const half8*)&As[(m_base + nl) * 136 + kc * 32 + quad * 8];
#pragma unroll
        for (int nt = 0; nt < 4; nt++) {
            half8 bb = *(const half8*)(W1h + (nt * 16 + nl) * DIN + kc * 32 + quad * 8);
            C[nt] = __builtin_amdgcn_mfma_f32_16x16x32_f16(a, bb, C[nt], 0, 0, 0);
        }
    }
    __syncthreads();   // all frag reads done before As is overwritten (stride-72 region)
#pragma unroll
    for (int nt = 0; nt < 4; nt++) {
        float bias = b1[nt * 16 + nl];
#pragma unroll
        for (int reg = 0; reg < 4; reg++) {
            int nd = m_base + quad * 4 + reg;
            float v = fmaxf(C[nt][reg] + bias, 0.f);
            As[nd * 72 + nt * 16 + nl] = __half_as_ushort(__float2half(v));
        }
    }
    __syncthreads();
    for (int i = t; i < 64 * 32; i += 256) {
        int nd = i >> 5, kp = i & 31;
        int node = node0 + nd;
        if (node < n)
            h0h2[(size_t)node * 32 + kp] = *(const __half2*)&As[nd * 72 + 2 * kp];
    }
}

__global__ void scan1(const int* __restrict__ cnt, int* __restrict__ row_start,
                      int* __restrict__ blocksum, int n) {
    __shared__ int sh[256];
    int t = threadIdx.x;
    int v = blockIdx.x * 256 + t;
    int val = (v < n) ? cnt[v] : 0;
    sh[t] = val;
    __syncthreads();
    for (int o = 1; o < 256; o <<= 1) {
        int y = (t >= o) ? sh[t - o] : 0;
        __syncthreads();
        sh[t] += y;
        __syncthreads();
    }
    if (v < n) row_start[v] = sh[t] - val;
    if (t == 255) blocksum[blockIdx.x] = sh[255];
}

__global__ void scan2(int* __restrict__ blocksum, int nb) {
    __shared__ int sh[512];
    int t = threadIdx.x;
    int val = (t < nb) ? blocksum[t] : 0;
    sh[t] = val;
    __syncthreads();
    for (int o = 1; o < 512; o <<= 1) {
        int y = (t >= o) ? sh[t - o] : 0;
        __syncthreads();
        sh[t] += y;
        __syncthreads();
    }
    if (t < nb) blocksum[t] = sh[t] - val;
}

// scan3 + dinv fold
__global__ void scan3(int* __restrict__ row_start, const int* __restrict__ blocksum,
                      const int* __restrict__ cnt, float* __restrict__ dinv, int n) {
    int v = blockIdx.x * 256 + threadIdx.x;
    if (v < n) {
        row_start[v] += blocksum[v >> 8];
        dinv[v] = rsqrtf((float)(cnt[v] + 1));
    }
}

// ---------- merged: scatter_pos + hp = dinv*h0h (fp16 + optional fp8 copy) --------
// blocks [0,GS): atomic-free CSR scatter; blocks [GS,GS+GH): hp scaling grid-stride.
__global__ void __launch_bounds__(256) scatter_hp(
        const uint32_t* __restrict__ ei, const int* __restrict__ flag,
        const int* __restrict__ row_start, const int* __restrict__ pw,
        int* __restrict__ csr_src, int E,
        const __half2* __restrict__ h0h2, const float* __restrict__ dinv,
        __half2* __restrict__ hp2, unsigned char* __restrict__ hp8,
        int use8, int n, int GS, int GH) {
    int b = blockIdx.x;
    int t = threadIdx.x;
    if (b < GS) {
        int e = b * 256 + t;
        if (e < E) {
            int is64 = *flag;
            int s = edge_src(ei, is64, E, e);
            int d = edge_dst(ei, is64, E, e);
            csr_src[row_start[d] + pw[e]] = s;
        }
        return;
    }
    int total = n * 32;
    for (int idx = (b - GS) * 256 + t; idx < total; idx += GH * 256) {
        int node = idx >> 5;
        float dv = dinv[node];
        float2 f = __half22float2(h0h2[idx]);
        float a = f.x * dv, bb = f.y * dv;
        hp2[idx] = __floats2half2_rn(a, bb);
        if (use8) {
            unsigned p = (unsigned)__builtin_amdgcn_cvt_pk_fp8_f32(a, bb, 0, false);
            ((ushort*)hp8)[idx] = (ushort)(p & 0xffffu);
        }
    }
}

// ---------- fused layer v13.3: fp8 gather when workspace allows, else fp16 --------
// 256 threads = 32 groups x 8 lanes; 32-node tile; group g owns node node0+g.
// Lane sub owns feature chunk [sub*8, sub*8+8). use8: neighbor rows from the fp8
// copy (64B rows = 1 cache line, HW cvt unpack); else proven R7 fp16 gather.
// Self-term + residual always fp16. Last layer fuses y = h@W2 + b2.
__global__ void __launch_bounds__(256) gcnii_fused(
        const __half* __restrict__ hp, const unsigned char* __restrict__ hp8,
        const __half* __restrict__ h0,
        const int* __restrict__ row_start, const int* __restrict__ csr_src,
        const float* __restrict__ dinv, const __half* __restrict__ Bp,
        const __half* __restrict__ W2h, const __half* __restrict__ W2l,
        const float* __restrict__ b2, int is_last, int use8,
        __half* __restrict__ hpn, unsigned char* __restrict__ hpn8,
        float* __restrict__ y, int n, int E) {
    __shared__ __align__(16) ushort Bs[64 * 72];       // B' [n][k], pad +8    9216B
    __shared__ __align__(16) ushort As[32 * 72];       // rows / result        4608B
    __shared__ int csr_lds[CSR_CAP];                   //                      3072B
    __shared__ int rs_lds[33];                         // row offsets rel. to ts
    int t = threadIdx.x;
    int node0 = blockIdx.x * 32;
    int grp = t >> 3, sub = t & 7;                     // 32 groups x 8 lanes

    // ---- stage B', CSR slice, row offsets (all independent loads) ----
    for (int i = t; i < 512; i += 256) {
        int bn = i >> 3, s8 = i & 7;
        *(half8*)&Bs[bn * 72 + s8 * 8] = *(const half8*)(Bp + bn * 64 + s8 * 8);
    }
    int ts = row_start[node0];                         // broadcast load
    int te = (node0 + 32 < n) ? row_start[node0 + 32] : E;
    int ne = te - ts;
    int staged = ne < CSR_CAP ? ne : CSR_CAP;
    for (int i = t; i < staged; i += 256) csr_lds[i] = csr_src[ts + i];
    if (t < 33) {
        int v = node0 + t;
        rs_lds[t] = ((v < n) ? row_start[v] : E) - ts;
    }
    __syncthreads();

    // ---- gather: group g accumulates node node0+g's neighbor rows ----
    int v = node0 + grp;
    int j = rs_lds[grp];
    int end = rs_lds[grp + 1];
    float acc[8];
#pragma unroll
    for (int q = 0; q < 8; q++) acc[q] = 0.f;
    if (use8) {
        // fp8 path: 8B/lane, one 64B line per row
        if (ne <= CSR_CAP) {
            int e = j;
            for (; e + 4 <= end; e += 4) {
                int s0 = csr_lds[e],     s1 = csr_lds[e + 1];
                int s2 = csr_lds[e + 2], s3 = csr_lds[e + 3];
                if ((unsigned)s0 >= (unsigned)n) s0 = 0;   // fault insurance
                if ((unsigned)s1 >= (unsigned)n) s1 = 0;
                if ((unsigned)s2 >= (unsigned)n) s2 = 0;
                if ((unsigned)s3 >= (unsigned)n) s3 = 0;
                uint2 c0 = *(const uint2*)(hp8 + (size_t)s0 * 64 + sub * 8);
                uint2 c1 = *(const uint2*)(hp8 + (size_t)s1 * 64 + sub * 8);
                uint2 c2 = *(const uint2*)(hp8 + (size_t)s2 * 64 + sub * 8);
                uint2 c3 = *(const uint2*)(hp8 + (size_t)s3 * 64 + sub * 8);
                float f0[8], f1[8], f2[8], f3[8];
                cvt8(c0, f0); cvt8(c1, f1); cvt8(c2, f2); cvt8(c3, f3);
#pragma unroll
                for (int q = 0; q < 8; q++)
                    acc[q] += (f0[q] + f1[q]) + (f2[q] + f3[q]);
            }
            for (; e < end; ++e) {
                int s = csr_lds[e];
                if ((unsigned)s >= (unsigned)n) s = 0;
                uint2 c = *(const uint2*)(hp8 + (size_t)s * 64 + sub * 8);
                float f[8];
                cvt8(c, f);
#pragma unroll
                for (int q = 0; q < 8; q++) acc[q] += f[q];
            }
        } else {
            for (int e = j; e < end; ++e) {
                int s = csr_src[ts + e];
                if ((unsigned)s >= (unsigned)n) s = 0;
                uint2 c = *(const uint2*)(hp8 + (size_t)s * 64 + sub * 8);
                float f[8];
                cvt8(c, f);
#pragma unroll
                for (int q = 0; q < 8; q++) acc[q] += f[q];
            }
        }
    } else {
        // fp16 fallback path (proven R7 gather)
        if (ne <= CSR_CAP) {
            int e = j;
            for (; e + 4 <= end; e += 4) {
                int s0 = csr_lds[e],     s1 = csr_lds[e + 1];
                int s2 = csr_lds[e + 2], s3 = csr_lds[e + 3];
                if ((unsigned)s0 >= (unsigned)n) s0 = 0;
                if ((unsigned)s1 >= (unsigned)n) s1 = 0;
                if ((unsigned)s2 >= (unsigned)n) s2 = 0;
                if ((unsigned)s3 >= (unsigned)n) s3 = 0;
                half8 h0v = *(const half8*)(hp + (size_t)s0 * 64 + sub * 8);
                half8 h1v = *(const half8*)(hp + (size_t)s1 * 64 + sub * 8);
                half8 h2v = *(const half8*)(hp + (size_t)s2 * 64 + sub * 8);
                half8 h3v = *(const half8*)(hp + (size_t)s3 * 64 + sub * 8);
#pragma unroll
                for (int q = 0; q < 8; q++)
                    acc[q] += ((float)h0v[q] + (float)h1v[q]) +
                              ((float)h2v[q] + (float)h3v[q]);
            }
            for (; e < end; ++e) {
                int s = csr_lds[e];
                if ((unsigned)s >= (unsigned)n) s = 0;
                half8 hv = *(const half8*)(hp + (size_t)s * 64 + sub * 8);
#pragma unroll
                for (int q = 0; q < 8; q++) acc[q] += (float)hv[q];
            }
        } else {
            for (int e = j; e < end; ++e) {
                int s = csr_src[ts + e];
                if ((unsigned)s >= (unsigned)n) s = 0;
                half8 hv = *(const half8*)(hp + (size_t)s * 64 + sub * 8);
#pragma unroll
                for (int q = 0; q < 8; q++) acc[q] += (float)hv[q];
            }
        }
    }
    // ---- blend + fp16 pack (self term fp16 + residual) ----
    {
        half8 o;
        if (v < n) {
            float sc = 0.9f * dinv[v];
            half8 hsv = *(const half8*)(hp + (size_t)v * 64 + sub * 8);
            half8 h0v = *(const half8*)(h0 + (size_t)v * 64 + sub * 8);
#pragma unroll
            for (int q = 0; q < 8; q++)
                o[q] = (_Float16)(sc * (acc[q] + (float)hsv[q]) + 0.1f * (float)h0v[q]);
        } else {
#pragma unroll
            for (int q = 0; q < 8; q++) o[q] = (_Float16)0.f;
        }
        *(half8*)&As[grp * 72 + sub * 8] = o;
    }
    __syncthreads();
    // ---- MFMA 32x64 = 2 strips x 4 col-tiles over 4 waves ----
    int lane = t & 63, w = t >> 6;
    int nl = lane & 15, quad = lane >> 4;
    int strip = w & 1, nth = w >> 1;
    f32x4 C[2];
    C[0] = (f32x4)0.f; C[1] = (f32x4)0.f;
#pragma unroll
    for (int kc = 0; kc < 2; kc++) {
        half8 a = *(const half8*)&As[(strip * 16 + nl) * 72 + kc * 32 + quad * 8];
#pragma unroll
        for (int t2 = 0; t2 < 2; t2++) {
            int nt = nth * 2 + t2;
            half8 b = *(const half8*)&Bs[(nt * 16 + nl) * 72 + kc * 32 + quad * 8];
            C[t2] = __builtin_amdgcn_mfma_f32_16x16x32_f16(a, b, C[t2], 0, 0, 0);
        }
    }
    __syncthreads();   // strips shared by 2 waves: finish all As reads before writes
#pragma unroll
    for (int reg = 0; reg < 4; reg++) {
        int nd = strip * 16 + quad * 4 + reg;
        int node = node0 + nd;
        float dv = (!is_last && node < n) ? dinv[node] : 1.f;
#pragma unroll
        for (int t2 = 0; t2 < 2; t2++) {
            int nt = nth * 2 + t2;
            float vv = fmaxf(C[t2][reg], 0.f) * dv;
            As[nd * 72 + nt * 16 + nl] = __half_as_ushort(__float2half(vv));
        }
    }
    __syncthreads();
    if (!is_last) {
        // ---- coalesced stores: fp16 row (16B) + optional fp8 row (8B) ----
        int nd = t >> 3, s8 = t & 7;
        int node = node0 + nd;
        if (node < n) {
            half8 hv = *(const half8*)&As[nd * 72 + s8 * 8];
            *(half8*)(hpn + (size_t)node * 64 + s8 * 8) = hv;
            if (use8) {
                float f[8];
#pragma unroll
                for (int q = 0; q < 8; q++) f[q] = (float)hv[q];
                *(uint2*)(hpn8 + (size_t)node * 64 + s8 * 8) = pack_fp8x8(f);
            }
        }
    } else {
        // ---- fused output: y = h @ W2 + b2 (double-fp16 W2, f32 accum) ----
        for (int ct = nth; ct < 3; ct += 2) {
            f32x4 C2 = (f32x4)0.f;
#pragma unroll
            for (int kc = 0; kc < 2; kc++) {
                half8 a  = *(const half8*)&As[(strip * 16 + nl) * 72 + kc * 32 + quad * 8];
                half8 bh = *(const half8*)(W2h + (ct * 16 + nl) * 64 + kc * 32 + quad * 8);
                half8 bl = *(const half8*)(W2l + (ct * 16 + nl) * 64 + kc * 32 + quad * 8);
                C2 = __builtin_amdgcn_mfma_f32_16x16x32_f16(a, bh, C2, 0, 0, 0);
                C2 = __builtin_amdgcn_mfma_f32_16x16x32_f16(a, bl, C2, 0, 0, 0);
            }
            int col = ct * 16 + nl;
            float bias = (col < DOUT) ? b2[col] : 0.f;
#pragma unroll
            for (int reg = 0; reg < 4; reg++) {
                int nd = strip * 16 + quad * 4 + reg;
                int node = node0 + nd;
                if (node < n && col < DOUT)
                    y[(size_t)node * DOUT + col] = C2[reg] + bias;
            }
        }
    }
}

extern "C" void kernel_launch(void* const* d_in, const int* in_sizes, int n_in,
                              void* d_out, int out_size, void* d_ws, size_t ws_size,
                              hipStream_t stream) {
    const float*    x     = (const float*)d_in[0];
    const uint32_t* ei    = (const uint32_t*)d_in[1];
    const float*    W1    = (const float*)d_in[2];
    const float*    b1    = (const float*)d_in[3];
    const float*    convw = (const float*)d_in[4];
    const float*    W2    = (const float*)d_in[5];
    const float*    b2    = (const float*)d_in[6];
    float*          y     = (float*)d_out;

    int N = in_sizes[0] / DIN;
    int E = in_sizes[1] / 2;

    char* ws = (char*)d_ws;
    size_t off = 0;
    auto alloc = [&](size_t bytes) -> char* {
        char* p = ws + off;
        off = (off + bytes + 255) & ~(size_t)255;
        return p;
    };
    int*     flag      = (int*)alloc(4);
    int*     cnt       = (int*)alloc((size_t)N * 4);
    int*     row_start = (int*)alloc((size_t)N * 4);
    float*   dinv      = (float*)alloc((size_t)N * 4);
    int*     blocksum  = (int*)alloc(512 * 4);
    int*     pw        = (int*)alloc((size_t)E * 4);
    int*     csr_src   = (int*)alloc((size_t)E * 4);
    __half*  Bp        = (__half*)alloc((size_t)N_LAYERS * HID * HID * 2);
    __half*  W1h       = (__half*)alloc((size_t)DIN * HID * 2);
    __half*  W2h       = (__half*)alloc((size_t)48 * HID * 2);
    __half*  W2l       = (__half*)alloc((size_t)48 * HID * 2);
    __half*  h0h       = (__half*)alloc((size_t)N * HID * 2);
    __half*  hpA       = (__half*)alloc((size_t)N * HID * 2);
    __half*  hpB       = (__half*)alloc((size_t)N * HID * 2);

    // fp8 gather copies: allocate ONLY if they fit in the workspace (overflow guard)
    unsigned char* hp8A = nullptr;
    unsigned char* hp8B = nullptr;
    size_t need8 = 2 * (((size_t)N * HID + 255) & ~(size_t)255) + 512;
    int use8 = (off + need8 <= ws_size) ? 1 : 0;
    if (use8) {
        hp8A = (unsigned char*)alloc((size_t)N * HID);
        hp8B = (unsigned char*)alloc((size_t)N * HID);
    }

    int nb = cdiv(N, 256);
    setup<<<nb + N_LAYERS + 3, 256, 0, stream>>>(ei, flag, convw, Bp, W1, W1h,
                                                 W2, W2h, W2l, cnt, N, nb);
    int GC = cdiv(E, 256);
    int GM = cdiv(N, 64);
    count_mlp<<<GC + GM, 256, 0, stream>>>(ei, flag, cnt, pw, E,
                                           x, W1h, b1, (__half2*)h0h, N, GC);
    scan1<<<nb, 256, 0, stream>>>(cnt, row_start, blocksum, N);
    scan2<<<1, 512, 0, stream>>>(blocksum, nb);
    scan3<<<cdiv(N, 256), 256, 0, stream>>>(row_start, blocksum, cnt, dinv, N);
    int GS = cdiv(E, 256);
    int GH = 512;
    scatter_hp<<<GS + GH, 256, 0, stream>>>(ei, flag, row_start, pw, csr_src, E,
                                            (const __half2*)h0h, dinv,
                                            (__half2*)hpA, hp8A, use8, N, GS, GH);

    __half* cur = hpA;
    __half* nxt = hpB;
    unsigned char* cur8 = hp8A;
    unsigned char* nxt8 = hp8B;
    for (int i = 0; i < N_LAYERS; i++) {
        int is_last = (i == N_LAYERS - 1) ? 1 : 0;
        gcnii_fused<<<cdiv(N, 32), 256, 0, stream>>>(
            cur, cur8, h0h, row_start, csr_src, dinv,
            Bp + (size_t)i * HID * HID, W2h, W2l, b2, is_last, use8,
            nxt, nxt8, y, N, E);
        __half* tmp = cur; cur = nxt; nxt = tmp;
        unsigned char* tmp8 = cur8; cur8 = nxt8; nxt8 = tmp8;
    }
}